// Round 2
// baseline (288.796 us; speedup 1.0000x reference)
//
#include <hip/hip_runtime.h>
#include <math.h>

// MPS-RNN 2D forward: L=8, M=8, DCUT=6, HL=2, N=64, B=32768
// One thread per batch sample; v_state in LDS (runtime column index j),
// everything else in registers; params via wave-uniform scalar loads.
// Output: harness compares float32 real part (astype of complex64) unless
// out_size == 2*B, in which case interleaved (re,im) pairs are expected.

#define LROWS 8
#define MCOLS 8
#define DC    6
#define NQ    64
#define BT    64   // threads per block

__global__ __launch_bounds__(BT, 1) void mps_rnn_kernel(
    const float* __restrict__ Mh,   // (L,M,2,6,6)
    const float* __restrict__ Mv,   // (L,M,2,6,6)
    const float* __restrict__ Vp,   // (L,M,2,6)
    const float* __restrict__ Tp,   // (L,M,2,6,6,6)
    const float* __restrict__ Wp,   // (L,M,6)
    const float* __restrict__ Cp,   // (L,M)
    const float* __restrict__ Ep,   // (L,M,6)  eta
    const int*   __restrict__ X,    // (B,64)
    float*       __restrict__ out,
    int Bn, int writeImag)
{
    __shared__ float vs[MCOLS * DC * BT];
    const int t = threadIdx.x;
    const int b = blockIdx.x * BT + t;
    if (b >= Bn) return;

    // ---- pack occupation bits into a u64 (no global reads inside the scan)
    unsigned long long bits = 0ull;
    {
        const int4* xr = reinterpret_cast<const int4*>(X + (size_t)b * NQ);
        #pragma unroll
        for (int q = 0; q < 16; ++q) {
            int4 v = xr[q];
            bits |= (unsigned long long)(v.x & 1) << (4 * q + 0);
            bits |= (unsigned long long)(v.y & 1) << (4 * q + 1);
            bits |= (unsigned long long)(v.z & 1) << (4 * q + 2);
            bits |= (unsigned long long)(v.w & 1) << (4 * q + 3);
        }
    }

    // ---- v_state = zeros (each thread owns its own LDS slots; no sync needed)
    #pragma unroll
    for (int s = 0; s < MCOLS * DC; ++s) vs[s * BT + t] = 0.f;

    float hh[DC];          // horizontal hidden state (set to 1 at each row start)
    float amp = 1.f, phi = 0.f;

    for (int k = 0; k < NQ; ++k) {
        const int i    = k >> 3;
        const int jm   = k & 7;
        const int j    = (i & 1) ? (MCOLS - 1 - jm) : jm;   // snake column
        const int site = i * MCOLS + j;

        const float* __restrict__ mh = Mh + site * 72;      // [a][o][c]
        const float* __restrict__ mv = Mv + site * 72;      // [a][o][c]
        const float* __restrict__ vk = Vp + site * 12;      // [a][o]
        const float* __restrict__ tk = Tp + site * 432;     // [a][o][c][d]
        const float* __restrict__ wk = Wp + site * 6;       // [o]
        const float* __restrict__ ek = Ep + site * 6;       // [o]
        const float ck = Cp[site];

        if (jm == 0) {                       // left boundary at row start
            #pragma unroll
            for (int o = 0; o < DC; ++o) hh[o] = 1.f;
        }

        float hv[DC];                        // vertical state for column j
        #pragma unroll
        for (int o = 0; o < DC; ++o) hv[o] = vs[(j * DC + o) * BT + t];

        // outer product h_h (x) h_v
        float pr[DC][DC];
        #pragma unroll
        for (int c = 0; c < DC; ++c)
            #pragma unroll
            for (int d = 0; d < DC; ++d) pr[c][d] = hh[c] * hv[d];

        // h_full[a][o] = hh[o] + hv[o] + V + Mh.hh + Mv.hv + T:(hh (x) hv)
        float hf[2][DC];
        #pragma unroll
        for (int a = 0; a < 2; ++a) {
            #pragma unroll
            for (int o = 0; o < DC; ++o) {
                float acc = vk[a * DC + o] + hh[o] + hv[o];
                const float* mhr = mh + (a * DC + o) * DC;
                const float* mvr = mv + (a * DC + o) * DC;
                const float* tr  = tk + (a * DC + o) * 36;
                #pragma unroll
                for (int c = 0; c < DC; ++c) acc = fmaf(mhr[c], hh[c], acc);
                #pragma unroll
                for (int c = 0; c < DC; ++c) acc = fmaf(mvr[c], hv[c], acc);
                #pragma unroll
                for (int c = 0; c < DC; ++c)
                    #pragma unroll
                    for (int d = 0; d < DC; ++d)
                        acc = fmaf(tr[c * DC + d], pr[c][d], acc);
                hf[a][o] = acc;
            }
        }

        // normalize over (a,o)
        float ss = 1e-12f;
        #pragma unroll
        for (int a = 0; a < 2; ++a)
            #pragma unroll
            for (int o = 0; o < DC; ++o) ss = fmaf(hf[a][o], hf[a][o], ss);
        const float inv = rsqrtf(ss);

        // q[a] = sum_o eta[o]^2 * h[a][o]^2
        float q0 = 0.f, q1 = 0.f;
        float hn[2][DC];
        #pragma unroll
        for (int a = 0; a < 2; ++a)
            #pragma unroll
            for (int o = 0; o < DC; ++o) {
                float h = hf[a][o] * inv;
                hn[a][o] = h;
                float e = ek[o];
                float w = (e * e) * (h * h);
                if (a == 0) q0 += w; else q1 += w;
            }

        const bool  sel  = (bits >> k) & 1ull;
        const float qs   = sel ? q1 : q0;
        const float psel = qs / (q0 + q1);
        amp *= sqrtf(psel);

        float ph = ck;
        #pragma unroll
        for (int o = 0; o < DC; ++o) {
            float h = sel ? hn[1][o] : hn[0][o];
            hh[o] = h;                                   // carry horizontally
            ph = fmaf(wk[o], h, ph);
        }
        phi += ph;

        #pragma unroll
        for (int o = 0; o < DC; ++o)                     // carry vertically
            vs[(j * DC + o) * BT + t] = hh[o];
    }

    if (writeImag) {
        out[2 * b + 0] = amp * cosf(phi);
        out[2 * b + 1] = amp * sinf(phi);
    } else {
        out[b] = amp * cosf(phi);      // harness compares real part (astype f32)
    }
}

extern "C" void kernel_launch(void* const* d_in, const int* in_sizes, int n_in,
                              void* d_out, int out_size, void* d_ws, size_t ws_size,
                              hipStream_t stream) {
    const float* Mh = (const float*)d_in[0];
    const float* Mv = (const float*)d_in[1];
    const float* Vp = (const float*)d_in[2];
    const float* Tp = (const float*)d_in[3];
    const float* Wp = (const float*)d_in[4];
    const float* Cp = (const float*)d_in[5];
    const float* Ep = (const float*)d_in[6];
    const int*   X  = (const int*)d_in[7];
    float* out = (float*)d_out;

    const int Bn = in_sizes[7] / NQ;                 // 32768
    const int writeImag = (out_size >= 2 * Bn) ? 1 : 0;
    const int grid = (Bn + BT - 1) / BT;             // 512 blocks

    mps_rnn_kernel<<<grid, BT, 0, stream>>>(Mh, Mv, Vp, Tp, Wp, Cp, Ep, X, out,
                                            Bn, writeImag);
}

// Round 3
// 287.070 us; speedup vs baseline: 1.0060x; 1.0060x over previous
//
#include <hip/hip_runtime.h>
#include <math.h>

// MPS-RNN 2D forward: L=8, M=8, DCUT=6, HL=2, N=64, B=32768
// 4 lanes per sample: lane sub in [0,4) owns rows r = sub*3 .. sub*3+2 of the
// 12 (a,o) pairs (a = sub>>1, o = (sub&1)*3 + lr). Cross-lane reductions via
// shfl within the aligned 4-lane group. v_state replicated per lane in LDS
// (stride-1 in lane => conflict-free). 131072 threads = 2048 waves = 8/CU.

#define MCOLS 8
#define DC    6
#define NQ    64
#define BT    256          // threads per block
#define SPB   (BT / 4)     // samples per block = 64

__global__ __launch_bounds__(BT, 1) void mps_rnn4(
    const float* __restrict__ Mh,   // (L,M,2,6,6)
    const float* __restrict__ Mv,   // (L,M,2,6,6)
    const float* __restrict__ Vp,   // (L,M,2,6)
    const float* __restrict__ Tp,   // (L,M,2,6,6,6)
    const float* __restrict__ Wp,   // (L,M,6)
    const float* __restrict__ Cp,   // (L,M)
    const float* __restrict__ Ep,   // (L,M,6)
    const int*   __restrict__ X,    // (B,64)
    float*       __restrict__ out,
    int Bn, int writeImag)
{
    __shared__ float vs[MCOLS * DC * BT];
    const int t   = threadIdx.x;
    const int sub = t & 3;
    const int b   = blockIdx.x * SPB + (t >> 2);
    if (b >= Bn) return;

    // ---- cooperative bit pack: each lane loads 16 qubits, OR-combine
    unsigned long long bits;
    {
        const int4* xr = reinterpret_cast<const int4*>(X + (size_t)b * NQ + sub * 16);
        unsigned long long part = 0ull;
        #pragma unroll
        for (int q = 0; q < 4; ++q) {
            int4 v = xr[q];
            part |= (unsigned long long)(v.x & 1) << (4 * q + 0);
            part |= (unsigned long long)(v.y & 1) << (4 * q + 1);
            part |= (unsigned long long)(v.z & 1) << (4 * q + 2);
            part |= (unsigned long long)(v.w & 1) << (4 * q + 3);
        }
        bits = part << (16 * sub);
        bits |= __shfl_xor(bits, 1, 64);
        bits |= __shfl_xor(bits, 2, 64);
    }

    // ---- v_state = zeros (per-lane private replicated slots, no sync needed)
    #pragma unroll
    for (int s = 0; s < MCOLS * DC; ++s) vs[s * BT + t] = 0.f;

    const int r0  = sub * 3;        // global row base (rows r0..r0+2)
    const int mya = sub >> 1;       // this lane's a
    const int ohi = sub & 1;        // 1 if this lane's o's are 3..5

    float hh[DC];                   // full h_h, replicated in all 4 lanes
    float amp = 1.f, phi = 0.f;

    for (int k = 0; k < NQ; ++k) {
        const int i    = k >> 3;
        const int jm   = k & 7;
        const int j    = (i & 1) ? (MCOLS - 1 - jm) : jm;
        const int site = i * MCOLS + j;

        if (jm == 0) {
            #pragma unroll
            for (int o = 0; o < DC; ++o) hh[o] = 1.f;
        }

        float hv[DC];
        #pragma unroll
        for (int o = 0; o < DC; ++o) hv[o] = vs[(j * DC + o) * BT + t];

        const float* __restrict__ mhp = Mh + site * 72 + r0 * 6;   // 18 floats
        const float* __restrict__ mvp = Mv + site * 72 + r0 * 6;   // 18 floats
        const float* __restrict__ tp  = Tp + site * 432 + r0 * 36; // 108 floats
        const float* __restrict__ vp  = Vp + site * 12 + r0;       // 3 floats
        const float* __restrict__ ep  = Ep + site * 6 + ohi * 3;   // 3 floats
        const float* __restrict__ wp  = Wp + site * 6;
        const float ck = Cp[site];

        float acc[3];
        #pragma unroll
        for (int lr = 0; lr < 3; ++lr) {
            // residual terms at this row's own o = ohi*3+lr (static idx + cndmask)
            const float hho = ohi ? hh[lr + 3] : hh[lr];
            const float hvo = ohi ? hv[lr + 3] : hv[lr];
            float a0 = vp[lr] + hho + hvo;
            #pragma unroll
            for (int c = 0; c < DC; ++c) a0 = fmaf(mhp[lr * 6 + c], hh[c], a0);
            #pragma unroll
            for (int c = 0; c < DC; ++c) a0 = fmaf(mvp[lr * 6 + c], hv[c], a0);
            #pragma unroll
            for (int c = 0; c < DC; ++c) {
                float sc = 0.f;
                #pragma unroll
                for (int d = 0; d < DC; ++d)
                    sc = fmaf(tp[lr * 36 + c * 6 + d], hv[d], sc);
                a0 = fmaf(sc, hh[c], a0);
            }
            acc[lr] = a0;
        }

        // ---- norm over all 12 rows (4-lane reduce)
        float ssp = acc[0] * acc[0] + acc[1] * acc[1] + acc[2] * acc[2];
        ssp += __shfl_xor(ssp, 1, 64);
        ssp += __shfl_xor(ssp, 2, 64);
        const float inv = rsqrtf(ssp + 1e-12f);

        // ---- q partials: lanes {0,1} hold a=0, {2,3} hold a=1
        float hn[3];
        float qp = 0.f;
        #pragma unroll
        for (int lr = 0; lr < 3; ++lr) {
            hn[lr] = acc[lr] * inv;
            const float e = ep[lr];
            qp = fmaf(e * e, hn[lr] * hn[lr], qp);
        }
        float q_a = qp + __shfl_xor(qp, 1, 64);   // q for this lane's a
        float q_o = __shfl_xor(q_a, 2, 64);       // q for the other a
        const int sel = (int)((bits >> k) & 1ull);
        const float q_sel = (mya == sel) ? q_a : q_o;
        amp *= sqrtf(q_sel / (q_a + q_o));

        // ---- rebuild h_sel (full 6-vector) in every lane
        const int lbase = (t & 63) & ~3;
        const int s0 = lbase + 2 * sel;     // lane holding o=0..2 of chosen a
        const int s1 = s0 + 1;              // lane holding o=3..5
        hh[0] = __shfl(hn[0], s0, 64);
        hh[1] = __shfl(hn[1], s0, 64);
        hh[2] = __shfl(hn[2], s0, 64);
        hh[3] = __shfl(hn[0], s1, 64);
        hh[4] = __shfl(hn[1], s1, 64);
        hh[5] = __shfl(hn[2], s1, 64);

        // ---- phase + vertical state update (all lanes, replicated)
        float ph = ck;
        #pragma unroll
        for (int o = 0; o < DC; ++o) ph = fmaf(wp[o], hh[o], ph);
        phi += ph;

        #pragma unroll
        for (int o = 0; o < DC; ++o) vs[(j * DC + o) * BT + t] = hh[o];
    }

    if (sub == 0) {
        if (writeImag) {
            out[2 * b + 0] = amp * cosf(phi);
            out[2 * b + 1] = amp * sinf(phi);
        } else {
            out[b] = amp * cosf(phi);
        }
    }
}

extern "C" void kernel_launch(void* const* d_in, const int* in_sizes, int n_in,
                              void* d_out, int out_size, void* d_ws, size_t ws_size,
                              hipStream_t stream) {
    const float* Mh = (const float*)d_in[0];
    const float* Mv = (const float*)d_in[1];
    const float* Vp = (const float*)d_in[2];
    const float* Tp = (const float*)d_in[3];
    const float* Wp = (const float*)d_in[4];
    const float* Cp = (const float*)d_in[5];
    const float* Ep = (const float*)d_in[6];
    const int*   X  = (const int*)d_in[7];
    float* out = (float*)d_out;

    const int Bn = in_sizes[7] / NQ;                 // 32768
    const int writeImag = (out_size >= 2 * Bn) ? 1 : 0;
    const int grid = (Bn + SPB - 1) / SPB;           // 512 blocks of 256 threads

    mps_rnn4<<<grid, BT, 0, stream>>>(Mh, Mv, Vp, Tp, Wp, Cp, Ep, X, out,
                                      Bn, writeImag);
}

// Round 4
// 285.057 us; speedup vs baseline: 1.0131x; 1.0071x over previous
//
#include <hip/hip_runtime.h>
#include <math.h>

// MPS-RNN 2D forward: L=8, M=8, DCUT=6, HL=2, N=64, B=32768
// 4 lanes/sample (rows r = sub*3..sub*3+2 of the 12 (a,o) pairs).
// Round-4 changes: batched per-row register loads (big reg window),
// tree-structured accumulators, rsqrt off the critical path
// (prob from unnormalized partials; bpermute acc then scale by inv).

#define MCOLS 8
#define DC    6
#define NQ    64
#define BT    256
#define SPB   (BT / 4)     // samples per block = 64

__global__ __launch_bounds__(BT, 1) void mps_rnn4(
    const float* __restrict__ Mh,   // (L,M,2,6,6)
    const float* __restrict__ Mv,   // (L,M,2,6,6)
    const float* __restrict__ Vp,   // (L,M,2,6)
    const float* __restrict__ Tp,   // (L,M,2,6,6,6)
    const float* __restrict__ Wp,   // (L,M,6)
    const float* __restrict__ Cp,   // (L,M)
    const float* __restrict__ Ep,   // (L,M,6)
    const int*   __restrict__ X,    // (B,64)
    float*       __restrict__ out,
    int Bn, int writeImag)
{
    __shared__ float vs[MCOLS * DC * BT];
    const int t   = threadIdx.x;
    const int sub = t & 3;
    const int b   = blockIdx.x * SPB + (t >> 2);
    if (b >= Bn) return;

    // cooperative bit pack (each lane 16 qubits, OR-combine across group)
    unsigned long long bits;
    {
        const int4* xr = reinterpret_cast<const int4*>(X + (size_t)b * NQ + sub * 16);
        unsigned long long part = 0ull;
        #pragma unroll
        for (int q = 0; q < 4; ++q) {
            int4 v = xr[q];
            part |= (unsigned long long)(v.x & 1) << (4 * q + 0);
            part |= (unsigned long long)(v.y & 1) << (4 * q + 1);
            part |= (unsigned long long)(v.z & 1) << (4 * q + 2);
            part |= (unsigned long long)(v.w & 1) << (4 * q + 3);
        }
        bits = part << (16 * sub);
        bits |= __shfl_xor(bits, 1, 64);
        bits |= __shfl_xor(bits, 2, 64);
    }

    #pragma unroll
    for (int s = 0; s < MCOLS * DC; ++s) vs[s * BT + t] = 0.f;

    const int r0  = sub * 3;        // row base
    const int mya = sub >> 1;       // this lane's a
    const int ohi = sub & 1;        // 1 if o's are 3..5

    float hh[DC];
    float amp = 1.f, phi = 0.f;

    for (int k = 0; k < NQ; ++k) {
        const int i    = k >> 3;
        const int jm   = k & 7;
        const int j    = (i & 1) ? (MCOLS - 1 - jm) : jm;
        const int site = i * MCOLS + j;

        // small per-step params (independent of state; issue early)
        float vv[3], ev[3];
        #pragma unroll
        for (int lr = 0; lr < 3; ++lr) {
            vv[lr] = Vp[site * 12 + r0 + lr];
            ev[lr] = Ep[site * 6 + ohi * 3 + lr];
        }
        float wf[6];
        {
            const float2* wv = reinterpret_cast<const float2*>(Wp + site * 6);
            #pragma unroll
            for (int q = 0; q < 3; ++q) { float2 a = wv[q]; wf[2*q] = a.x; wf[2*q+1] = a.y; }
        }
        const float ck = Cp[site];

        if (jm == 0) {
            #pragma unroll
            for (int o = 0; o < DC; ++o) hh[o] = 1.f;
        }

        float hv[DC];
        #pragma unroll
        for (int o = 0; o < DC; ++o) hv[o] = vs[(j * DC + o) * BT + t];

        float acc[3];
        #pragma unroll
        for (int lr = 0; lr < 3; ++lr) {
            // ---- batched register loads for this row (36 + 6 + 6 floats)
            const float4* tv  = reinterpret_cast<const float4*>(Tp + site * 432 + (r0 + lr) * 36);
            const float2* mhv = reinterpret_cast<const float2*>(Mh + site * 72 + (r0 + lr) * 6);
            const float2* mvv = reinterpret_cast<const float2*>(Mv + site * 72 + (r0 + lr) * 6);
            float tf[36];
            #pragma unroll
            for (int q = 0; q < 9; ++q) {
                float4 x = tv[q];
                tf[4*q] = x.x; tf[4*q+1] = x.y; tf[4*q+2] = x.z; tf[4*q+3] = x.w;
            }
            float mhf[6], mvf[6];
            #pragma unroll
            for (int q = 0; q < 3; ++q) {
                float2 a = mhv[q]; mhf[2*q] = a.x; mhf[2*q+1] = a.y;
                float2 c = mvv[q]; mvf[2*q] = c.x; mvf[2*q+1] = c.y;
            }

            const float hho = ohi ? hh[lr + 3] : hh[lr];
            const float hvo = ohi ? hv[lr + 3] : hv[lr];
            const float base = vv[lr] + hho + hvo;

            // T term: sc[c] = T[c][:]·hv, two independent sub-chains each
            float sc[6];
            #pragma unroll
            for (int c = 0; c < 6; ++c) {
                const int o0 = c * 6;
                float sa = fmaf(tf[o0+0], hv[0], fmaf(tf[o0+2], hv[2], tf[o0+4]*hv[4]));
                float sb = fmaf(tf[o0+1], hv[1], fmaf(tf[o0+3], hv[3], tf[o0+5]*hv[5]));
                sc[c] = sa + sb;
            }
            float p0 = fmaf(sc[0], hh[0], fmaf(sc[3], hh[3], base));
            float p1 = fmaf(sc[1], hh[1], sc[4] * hh[4]);
            float p2 = fmaf(sc[2], hh[2], sc[5] * hh[5]);
            float ma = fmaf(mhf[0], hh[0], fmaf(mhf[2], hh[2], mhf[4]*hh[4]));
            float mb = fmaf(mhf[1], hh[1], fmaf(mhf[3], hh[3], mhf[5]*hh[5]));
            float na = fmaf(mvf[0], hv[0], fmaf(mvf[2], hv[2], mvf[4]*hv[4]));
            float nb = fmaf(mvf[1], hv[1], fmaf(mvf[3], hv[3], mvf[5]*hv[5]));
            acc[lr] = ((p0 + p1) + (p2 + ma)) + ((mb + na) + nb);
        }

        // ---- 4-lane reductions on UNNORMALIZED acc (inv^2 cancels in prob)
        float ssl = fmaf(acc[0], acc[0], fmaf(acc[1], acc[1], acc[2]*acc[2]));
        float pq  = fmaf(ev[0]*ev[0], acc[0]*acc[0],
                    fmaf(ev[1]*ev[1], acc[1]*acc[1], (ev[2]*ev[2])*(acc[2]*acc[2])));
        ssl += __shfl_xor(ssl, 1, 64);
        pq  += __shfl_xor(pq,  1, 64);
        const float ssq = ssl + __shfl_xor(ssl, 2, 64);
        const float pqx = __shfl_xor(pq, 2, 64);
        const float inv = rsqrtf(ssq + 1e-12f);

        const int sel = (int)((bits >> k) & 1ull);
        const float qsel = (mya == sel) ? pq : pqx;
        amp *= sqrtf(qsel / (pq + pqx));

        // rebuild h_sel: bpermute unnormalized acc, then scale by inv
        const int lbase = (t & 63) & ~3;
        const int s0 = lbase + 2 * sel;
        const int s1 = s0 + 1;
        float u0 = __shfl(acc[0], s0, 64);
        float u1 = __shfl(acc[1], s0, 64);
        float u2 = __shfl(acc[2], s0, 64);
        float u3 = __shfl(acc[0], s1, 64);
        float u4 = __shfl(acc[1], s1, 64);
        float u5 = __shfl(acc[2], s1, 64);
        hh[0] = u0 * inv; hh[1] = u1 * inv; hh[2] = u2 * inv;
        hh[3] = u3 * inv; hh[4] = u4 * inv; hh[5] = u5 * inv;

        float ph = ck;
        #pragma unroll
        for (int o = 0; o < DC; ++o) ph = fmaf(wf[o], hh[o], ph);
        phi += ph;

        #pragma unroll
        for (int o = 0; o < DC; ++o) vs[(j * DC + o) * BT + t] = hh[o];
    }

    if (sub == 0) {
        if (writeImag) {
            out[2 * b + 0] = amp * cosf(phi);
            out[2 * b + 1] = amp * sinf(phi);
        } else {
            out[b] = amp * cosf(phi);
        }
    }
}

extern "C" void kernel_launch(void* const* d_in, const int* in_sizes, int n_in,
                              void* d_out, int out_size, void* d_ws, size_t ws_size,
                              hipStream_t stream) {
    const float* Mh = (const float*)d_in[0];
    const float* Mv = (const float*)d_in[1];
    const float* Vp = (const float*)d_in[2];
    const float* Tp = (const float*)d_in[3];
    const float* Wp = (const float*)d_in[4];
    const float* Cp = (const float*)d_in[5];
    const float* Ep = (const float*)d_in[6];
    const int*   X  = (const int*)d_in[7];
    float* out = (float*)d_out;

    const int Bn = in_sizes[7] / NQ;                 // 32768
    const int writeImag = (out_size >= 2 * Bn) ? 1 : 0;
    const int grid = (Bn + SPB - 1) / SPB;           // 512 blocks of 256 threads

    mps_rnn4<<<grid, BT, 0, stream>>>(Mh, Mv, Vp, Tp, Wp, Cp, Ep, X, out,
                                      Bn, writeImag);
}

// Round 5
// 118.094 us; speedup vs baseline: 2.4455x; 2.4138x over previous
//
#include <hip/hip_runtime.h>
#include <math.h>

// MPS-RNN 2D forward: L=8, M=8, DCUT=6, HL=2, N=64, B=32768
// 4 lanes/sample (rows r = sub*3..sub*3+2 of the 12 (a,o) pairs).
// Round-5: sliding double-buffered LDS staging of per-site params
// (issue global loads early, ds_write late, one barrier/step); v_state
// stored once per sample in LDS (broadcast read by the 4 lanes).

#define MCOLS 8
#define DC    6
#define NQ    64
#define BT    256
#define SPB   (BT / 4)     // samples per block = 64

// per-site param buffer layout (floats)
#define SITE_F 608         // padded (601 used)
#define T_OFF  0           // 432
#define MH_OFF 432         // 72
#define MV_OFF 504         // 72
#define V_OFF  576         // 12
#define W_OFF  588         // 6
#define E_OFF  594         // 6
#define C_OFF  600         // 1

__global__ __launch_bounds__(BT, 1) void mps_rnn5(
    const float* __restrict__ Mh,   // (L,M,2,6,6)
    const float* __restrict__ Mv,   // (L,M,2,6,6)
    const float* __restrict__ Vp,   // (L,M,2,6)
    const float* __restrict__ Tp,   // (L,M,2,6,6,6)
    const float* __restrict__ Wp,   // (L,M,6)
    const float* __restrict__ Cp,   // (L,M)
    const float* __restrict__ Ep,   // (L,M,6)
    const int*   __restrict__ X,    // (B,64)
    float*       __restrict__ out,
    int Bn, int writeImag)
{
    __shared__ float pbuf[2][SITE_F];
    __shared__ float vs[MCOLS * DC * SPB];   // [(j*6+o)*SPB + s]

    const int t   = threadIdx.x;
    const int sub = t & 3;
    const int s   = t >> 2;
    int b = blockIdx.x * SPB + s;
    const bool valid = (b < Bn);
    if (!valid) b = Bn - 1;          // clamp loads; no early return (barriers!)

    // staged-register set for the async param prefetch
    float4 sg4 = {0,0,0,0}; float2 sg2 = {0,0}; float sg1 = 0.f;

    auto stage_load = [&](int site) {
        if (t < 108)       sg4 = reinterpret_cast<const float4*>(Tp + site * 432)[t];
        else if (t < 126)  sg4 = reinterpret_cast<const float4*>(Mh + site * 72)[t - 108];
        else if (t < 144)  sg4 = reinterpret_cast<const float4*>(Mv + site * 72)[t - 126];
        else if (t < 147)  sg4 = reinterpret_cast<const float4*>(Vp + site * 12)[t - 144];
        else if (t < 150)  sg2 = reinterpret_cast<const float2*>(Wp + site * 6)[t - 147];
        else if (t < 153)  sg2 = reinterpret_cast<const float2*>(Ep + site * 6)[t - 150];
        else if (t == 153) sg1 = Cp[site];
    };
    auto stage_write = [&](float* B) {
        if (t < 108)       reinterpret_cast<float4*>(B + T_OFF)[t] = sg4;
        else if (t < 126)  reinterpret_cast<float4*>(B + MH_OFF)[t - 108] = sg4;
        else if (t < 144)  reinterpret_cast<float4*>(B + MV_OFF)[t - 126] = sg4;
        else if (t < 147)  reinterpret_cast<float4*>(B + V_OFF)[t - 144] = sg4;
        else if (t < 150)  reinterpret_cast<float2*>(B + W_OFF)[t - 147] = sg2;
        else if (t < 153)  reinterpret_cast<float2*>(B + E_OFF)[t - 150] = sg2;
        else if (t == 153) B[C_OFF] = sg1;
    };

    // cooperative bit pack (each lane 16 qubits, OR-combine across group)
    unsigned long long bits;
    {
        const int4* xr = reinterpret_cast<const int4*>(X + (size_t)b * NQ + sub * 16);
        unsigned long long part = 0ull;
        #pragma unroll
        for (int q = 0; q < 4; ++q) {
            int4 v = xr[q];
            part |= (unsigned long long)(v.x & 1) << (4 * q + 0);
            part |= (unsigned long long)(v.y & 1) << (4 * q + 1);
            part |= (unsigned long long)(v.z & 1) << (4 * q + 2);
            part |= (unsigned long long)(v.w & 1) << (4 * q + 3);
        }
        bits = part << (16 * sub);
        bits |= __shfl_xor(bits, 1, 64);
        bits |= __shfl_xor(bits, 2, 64);
    }

    // v_state zeros (one copy per sample)
    #pragma unroll
    for (int q = 0; q < (MCOLS * DC * SPB) / BT; ++q)
        vs[q * BT + t] = 0.f;

    // prologue: stage site 0 (site(k=0): i=0, j=0 -> site 0)
    stage_load(0);
    stage_write(pbuf[0]);
    __syncthreads();

    const int r0  = sub * 3;
    const int mya = sub >> 1;
    const int ohi = sub & 1;

    float hh[DC];
    float amp = 1.f, phi = 0.f;
    int cur = 0;

    #pragma unroll 2
    for (int k = 0; k < NQ; ++k) {
        const int i  = k >> 3;
        const int jm = k & 7;
        const int j  = (i & 1) ? (MCOLS - 1 - jm) : jm;

        // ---- issue next site's global loads EARLY (latency hides under compute)
        if (k < NQ - 1) {
            const int kn = k + 1;
            const int in = kn >> 3;
            const int jn = (in & 1) ? (MCOLS - 1 - (kn & 7)) : (kn & 7);
            stage_load(in * MCOLS + jn);
        }

        const float* __restrict__ P = pbuf[cur];

        if (jm == 0) {
            #pragma unroll
            for (int o = 0; o < DC; ++o) hh[o] = 1.f;
        }

        float hv[DC];
        #pragma unroll
        for (int o = 0; o < DC; ++o) hv[o] = vs[(j * DC + o) * SPB + s];

        float vv[3], ev[3];
        #pragma unroll
        for (int lr = 0; lr < 3; ++lr) {
            vv[lr] = P[V_OFF + r0 + lr];
            ev[lr] = P[E_OFF + ohi * 3 + lr];
        }
        float wf[6];
        #pragma unroll
        for (int o = 0; o < DC; ++o) wf[o] = P[W_OFF + o];
        const float ck = P[C_OFF];

        float acc[3];
        #pragma unroll
        for (int lr = 0; lr < 3; ++lr) {
            const float4* tv  = reinterpret_cast<const float4*>(P + T_OFF + (r0 + lr) * 36);
            const float2* mhv = reinterpret_cast<const float2*>(P + MH_OFF + (r0 + lr) * 6);
            const float2* mvv = reinterpret_cast<const float2*>(P + MV_OFF + (r0 + lr) * 6);
            float tf[36];
            #pragma unroll
            for (int q = 0; q < 9; ++q) {
                float4 x = tv[q];
                tf[4*q] = x.x; tf[4*q+1] = x.y; tf[4*q+2] = x.z; tf[4*q+3] = x.w;
            }
            float mhf[6], mvf[6];
            #pragma unroll
            for (int q = 0; q < 3; ++q) {
                float2 a = mhv[q]; mhf[2*q] = a.x; mhf[2*q+1] = a.y;
                float2 c = mvv[q]; mvf[2*q] = c.x; mvf[2*q+1] = c.y;
            }

            const float hho = ohi ? hh[lr + 3] : hh[lr];
            const float hvo = ohi ? hv[lr + 3] : hv[lr];
            const float base = vv[lr] + hho + hvo;

            float sc[6];
            #pragma unroll
            for (int c = 0; c < 6; ++c) {
                const int o0 = c * 6;
                float sa = fmaf(tf[o0+0], hv[0], fmaf(tf[o0+2], hv[2], tf[o0+4]*hv[4]));
                float sb = fmaf(tf[o0+1], hv[1], fmaf(tf[o0+3], hv[3], tf[o0+5]*hv[5]));
                sc[c] = sa + sb;
            }
            float p0 = fmaf(sc[0], hh[0], fmaf(sc[3], hh[3], base));
            float p1 = fmaf(sc[1], hh[1], sc[4] * hh[4]);
            float p2 = fmaf(sc[2], hh[2], sc[5] * hh[5]);
            float ma = fmaf(mhf[0], hh[0], fmaf(mhf[2], hh[2], mhf[4]*hh[4]));
            float mb = fmaf(mhf[1], hh[1], fmaf(mhf[3], hh[3], mhf[5]*hh[5]));
            float na = fmaf(mvf[0], hv[0], fmaf(mvf[2], hv[2], mvf[4]*hv[4]));
            float nb = fmaf(mvf[1], hv[1], fmaf(mvf[3], hv[3], mvf[5]*hv[5]));
            acc[lr] = ((p0 + p1) + (p2 + ma)) + ((mb + na) + nb);
        }

        // 4-lane reductions on UNNORMALIZED acc (inv^2 cancels in prob)
        float ssl = fmaf(acc[0], acc[0], fmaf(acc[1], acc[1], acc[2]*acc[2]));
        float pq  = fmaf(ev[0]*ev[0], acc[0]*acc[0],
                    fmaf(ev[1]*ev[1], acc[1]*acc[1], (ev[2]*ev[2])*(acc[2]*acc[2])));
        ssl += __shfl_xor(ssl, 1, 64);
        pq  += __shfl_xor(pq,  1, 64);
        const float ssq = ssl + __shfl_xor(ssl, 2, 64);
        const float pqx = __shfl_xor(pq, 2, 64);
        const float inv = rsqrtf(ssq + 1e-12f);

        const int sel = (int)((bits >> k) & 1ull);
        const float qsel = (mya == sel) ? pq : pqx;
        amp *= sqrtf(qsel / (pq + pqx));

        // rebuild h_sel: shfl unnormalized acc, scale by inv
        const int lbase = (t & 63) & ~3;
        const int s0 = lbase + 2 * sel;
        const int s1 = s0 + 1;
        hh[0] = __shfl(acc[0], s0, 64) * inv;
        hh[1] = __shfl(acc[1], s0, 64) * inv;
        hh[2] = __shfl(acc[2], s0, 64) * inv;
        hh[3] = __shfl(acc[0], s1, 64) * inv;
        hh[4] = __shfl(acc[1], s1, 64) * inv;
        hh[5] = __shfl(acc[2], s1, 64) * inv;

        float ph = ck;
        #pragma unroll
        for (int o = 0; o < DC; ++o) ph = fmaf(wf[o], hh[o], ph);
        phi += ph;

        if (sub == 0) {
            #pragma unroll
            for (int o = 0; o < DC; ++o) vs[(j * DC + o) * SPB + s] = hh[o];
        }

        // ---- write staged params LATE, then one barrier per step
        if (k < NQ - 1) {
            stage_write(pbuf[cur ^ 1]);
            __syncthreads();
            cur ^= 1;
        }
    }

    if (sub == 0 && valid) {
        if (writeImag) {
            out[2 * b + 0] = amp * cosf(phi);
            out[2 * b + 1] = amp * sinf(phi);
        } else {
            out[b] = amp * cosf(phi);
        }
    }
}

extern "C" void kernel_launch(void* const* d_in, const int* in_sizes, int n_in,
                              void* d_out, int out_size, void* d_ws, size_t ws_size,
                              hipStream_t stream) {
    const float* Mh = (const float*)d_in[0];
    const float* Mv = (const float*)d_in[1];
    const float* Vp = (const float*)d_in[2];
    const float* Tp = (const float*)d_in[3];
    const float* Wp = (const float*)d_in[4];
    const float* Cp = (const float*)d_in[5];
    const float* Ep = (const float*)d_in[6];
    const int*   X  = (const int*)d_in[7];
    float* out = (float*)d_out;

    const int Bn = in_sizes[7] / NQ;                 // 32768
    const int writeImag = (out_size >= 2 * Bn) ? 1 : 0;
    const int grid = (Bn + SPB - 1) / SPB;           // 512 blocks of 256 threads

    mps_rnn5<<<grid, BT, 0, stream>>>(Mh, Mv, Vp, Tp, Wp, Cp, Ep, X, out,
                                      Bn, writeImag);
}

// Round 6
// 102.554 us; speedup vs baseline: 2.8160x; 1.1515x over previous
//
#include <hip/hip_runtime.h>
#include <math.h>

// MPS-RNN 2D forward: L=8, M=8, DCUT=6, HL=2, N=64, B=32768
// 4 lanes/sample (rows r = sub*3..sub*3+2 of the 12 (a,o) pairs).
// Round-6: chunk-resident params. A 16-site chunk (two snake rows,
// contiguous in all param arrays) lives in LDS; 16 steps run with no
// barriers and no global traffic; re-stage 4x per kernel.

#define MCOLS 8
#define DC    6
#define NQ    64
#define BT    256
#define SPB   (BT / 4)     // samples per block = 64

// LDS float offsets for a 16-site chunk (38464 B total)
#define TL    0            // 16*432 = 6912
#define MHL   6912         // 16*72  = 1152
#define MVL   8064         // 16*72  = 1152
#define VL    9216         // 16*12  = 192
#define WL    9408         // 16*6   = 96
#define EL    9504         // 16*6   = 96
#define CL    9600         // 16*1   = 16
#define PARAM_F 9616

__global__ __launch_bounds__(BT, 1) void mps_rnn6(
    const float* __restrict__ Mh,   // (L,M,2,6,6)
    const float* __restrict__ Mv,   // (L,M,2,6,6)
    const float* __restrict__ Vp,   // (L,M,2,6)
    const float* __restrict__ Tp,   // (L,M,2,6,6,6)
    const float* __restrict__ Wp,   // (L,M,6)
    const float* __restrict__ Cp,   // (L,M)
    const float* __restrict__ Ep,   // (L,M,6)
    const int*   __restrict__ X,    // (B,64)
    float*       __restrict__ out,
    int Bn, int writeImag)
{
    __shared__ float ps[PARAM_F];
    __shared__ float vs[MCOLS * DC * SPB];   // [(j*6+o)*SPB + s]

    const int t   = threadIdx.x;
    const int sub = t & 3;
    const int s   = t >> 2;
    int b = blockIdx.x * SPB + s;
    const bool valid = (b < Bn);
    if (!valid) b = Bn - 1;          // clamp loads; no early return (barriers!)

    // cooperative bit pack (each lane 16 qubits, OR-combine across group)
    unsigned long long bits;
    {
        const int4* xr = reinterpret_cast<const int4*>(X + (size_t)b * NQ + sub * 16);
        unsigned long long part = 0ull;
        #pragma unroll
        for (int q = 0; q < 4; ++q) {
            int4 v = xr[q];
            part |= (unsigned long long)(v.x & 1) << (4 * q + 0);
            part |= (unsigned long long)(v.y & 1) << (4 * q + 1);
            part |= (unsigned long long)(v.z & 1) << (4 * q + 2);
            part |= (unsigned long long)(v.w & 1) << (4 * q + 3);
        }
        bits = part << (16 * sub);
        bits |= __shfl_xor(bits, 1, 64);
        bits |= __shfl_xor(bits, 2, 64);
    }

    // v_state zeros (one copy per sample)
    #pragma unroll
    for (int q = 0; q < (MCOLS * DC * SPB) / BT; ++q)
        vs[q * BT + t] = 0.f;

    const int r0  = sub * 3;
    const int mya = sub >> 1;
    const int ohi = sub & 1;

    float hh[DC];
    float amp = 1.f, phi = 0.f;

    for (int ch = 0; ch < 4; ++ch) {
        // ---- stage chunk ch: sites 16*ch .. 16*ch+15 (contiguous per array)
        __syncthreads();             // all waves done reading previous chunk
        {
            const float4* g; float4* l;
            g = reinterpret_cast<const float4*>(Tp + ch * 6912);
            l = reinterpret_cast<float4*>(ps + TL);
            #pragma unroll
            for (int idx = t; idx < 1728; idx += BT) l[idx] = g[idx];
            g = reinterpret_cast<const float4*>(Mh + ch * 1152);
            l = reinterpret_cast<float4*>(ps + MHL);
            #pragma unroll
            for (int idx = t; idx < 288; idx += BT) l[idx] = g[idx];
            g = reinterpret_cast<const float4*>(Mv + ch * 1152);
            l = reinterpret_cast<float4*>(ps + MVL);
            #pragma unroll
            for (int idx = t; idx < 288; idx += BT) l[idx] = g[idx];
            if (t < 48)  reinterpret_cast<float4*>(ps + VL)[t] =
                         reinterpret_cast<const float4*>(Vp + ch * 192)[t];
            else if (t < 72)  reinterpret_cast<float4*>(ps + WL)[t - 48] =
                         reinterpret_cast<const float4*>(Wp + ch * 96)[t - 48];
            else if (t < 96)  reinterpret_cast<float4*>(ps + EL)[t - 72] =
                         reinterpret_cast<const float4*>(Ep + ch * 96)[t - 72];
            else if (t < 100) reinterpret_cast<float4*>(ps + CL)[t - 96] =
                         reinterpret_cast<const float4*>(Cp + ch * 16)[t - 96];
        }
        __syncthreads();             // chunk visible

        #pragma unroll 2
        for (int kk = 0; kk < 16; ++kk) {
            const int k  = ch * 16 + kk;
            const int ih = kk >> 3;              // 0/1: which row of the chunk
            const int jm = kk & 7;
            const int j  = ih ? (7 - jm) : jm;   // chunk rows are (even,odd)
            const int slot = (ih << 3) + j;

            const float* __restrict__ Ts  = ps + TL  + slot * 432;
            const float* __restrict__ MHs = ps + MHL + slot * 72;
            const float* __restrict__ MVs = ps + MVL + slot * 72;
            const float* __restrict__ Vs  = ps + VL  + slot * 12;
            const float* __restrict__ Ws  = ps + WL  + slot * 6;
            const float* __restrict__ Es  = ps + EL  + slot * 6;
            const float ck = ps[CL + slot];

            if (jm == 0) {
                #pragma unroll
                for (int o = 0; o < DC; ++o) hh[o] = 1.f;
            }

            float hv[DC];
            #pragma unroll
            for (int o = 0; o < DC; ++o) hv[o] = vs[(j * DC + o) * SPB + s];

            float vv[3], ev[3];
            #pragma unroll
            for (int lr = 0; lr < 3; ++lr) {
                vv[lr] = Vs[r0 + lr];
                ev[lr] = Es[ohi * 3 + lr];
            }
            float wf[6];
            #pragma unroll
            for (int o = 0; o < DC; ++o) wf[o] = Ws[o];

            float acc[3];
            #pragma unroll
            for (int lr = 0; lr < 3; ++lr) {
                const float4* tv  = reinterpret_cast<const float4*>(Ts + (r0 + lr) * 36);
                const float2* mhv = reinterpret_cast<const float2*>(MHs + (r0 + lr) * 6);
                const float2* mvv = reinterpret_cast<const float2*>(MVs + (r0 + lr) * 6);
                float tf[36];
                #pragma unroll
                for (int q = 0; q < 9; ++q) {
                    float4 x = tv[q];
                    tf[4*q] = x.x; tf[4*q+1] = x.y; tf[4*q+2] = x.z; tf[4*q+3] = x.w;
                }
                float mhf[6], mvf[6];
                #pragma unroll
                for (int q = 0; q < 3; ++q) {
                    float2 a = mhv[q]; mhf[2*q] = a.x; mhf[2*q+1] = a.y;
                    float2 c = mvv[q]; mvf[2*q] = c.x; mvf[2*q+1] = c.y;
                }

                const float hho = ohi ? hh[lr + 3] : hh[lr];
                const float hvo = ohi ? hv[lr + 3] : hv[lr];
                const float base = vv[lr] + hho + hvo;

                float sc[6];
                #pragma unroll
                for (int c = 0; c < 6; ++c) {
                    const int o0 = c * 6;
                    float sa = fmaf(tf[o0+0], hv[0], fmaf(tf[o0+2], hv[2], tf[o0+4]*hv[4]));
                    float sb = fmaf(tf[o0+1], hv[1], fmaf(tf[o0+3], hv[3], tf[o0+5]*hv[5]));
                    sc[c] = sa + sb;
                }
                float p0 = fmaf(sc[0], hh[0], fmaf(sc[3], hh[3], base));
                float p1 = fmaf(sc[1], hh[1], sc[4] * hh[4]);
                float p2 = fmaf(sc[2], hh[2], sc[5] * hh[5]);
                float ma = fmaf(mhf[0], hh[0], fmaf(mhf[2], hh[2], mhf[4]*hh[4]));
                float mb = fmaf(mhf[1], hh[1], fmaf(mhf[3], hh[3], mhf[5]*hh[5]));
                float na = fmaf(mvf[0], hv[0], fmaf(mvf[2], hv[2], mvf[4]*hv[4]));
                float nb = fmaf(mvf[1], hv[1], fmaf(mvf[3], hv[3], mvf[5]*hv[5]));
                acc[lr] = ((p0 + p1) + (p2 + ma)) + ((mb + na) + nb);
            }

            // 4-lane reductions on UNNORMALIZED acc (inv^2 cancels in prob)
            float ssl = fmaf(acc[0], acc[0], fmaf(acc[1], acc[1], acc[2]*acc[2]));
            float pq  = fmaf(ev[0]*ev[0], acc[0]*acc[0],
                        fmaf(ev[1]*ev[1], acc[1]*acc[1], (ev[2]*ev[2])*(acc[2]*acc[2])));
            ssl += __shfl_xor(ssl, 1, 64);
            pq  += __shfl_xor(pq,  1, 64);
            const float ssq = ssl + __shfl_xor(ssl, 2, 64);
            const float pqx = __shfl_xor(pq, 2, 64);
            const float inv = rsqrtf(ssq + 1e-12f);

            const int sel = (int)((bits >> k) & 1ull);
            const float qsel = (mya == sel) ? pq : pqx;
            amp *= sqrtf(qsel / (pq + pqx));

            // rebuild h_sel: shfl unnormalized acc, scale by inv
            const int lbase = (t & 63) & ~3;
            const int s0 = lbase + 2 * sel;
            const int s1 = s0 + 1;
            hh[0] = __shfl(acc[0], s0, 64) * inv;
            hh[1] = __shfl(acc[1], s0, 64) * inv;
            hh[2] = __shfl(acc[2], s0, 64) * inv;
            hh[3] = __shfl(acc[0], s1, 64) * inv;
            hh[4] = __shfl(acc[1], s1, 64) * inv;
            hh[5] = __shfl(acc[2], s1, 64) * inv;

            float ph = ck;
            #pragma unroll
            for (int o = 0; o < DC; ++o) ph = fmaf(wf[o], hh[o], ph);
            phi += ph;

            if (sub == 0) {
                #pragma unroll
                for (int o = 0; o < DC; ++o) vs[(j * DC + o) * SPB + s] = hh[o];
            }
        }
    }

    if (sub == 0 && valid) {
        if (writeImag) {
            out[2 * b + 0] = amp * cosf(phi);
            out[2 * b + 1] = amp * sinf(phi);
        } else {
            out[b] = amp * cosf(phi);
        }
    }
}

extern "C" void kernel_launch(void* const* d_in, const int* in_sizes, int n_in,
                              void* d_out, int out_size, void* d_ws, size_t ws_size,
                              hipStream_t stream) {
    const float* Mh = (const float*)d_in[0];
    const float* Mv = (const float*)d_in[1];
    const float* Vp = (const float*)d_in[2];
    const float* Tp = (const float*)d_in[3];
    const float* Wp = (const float*)d_in[4];
    const float* Cp = (const float*)d_in[5];
    const float* Ep = (const float*)d_in[6];
    const int*   X  = (const int*)d_in[7];
    float* out = (float*)d_out;

    const int Bn = in_sizes[7] / NQ;                 // 32768
    const int writeImag = (out_size >= 2 * Bn) ? 1 : 0;
    const int grid = (Bn + SPB - 1) / SPB;           // 512 blocks of 256 threads

    mps_rnn6<<<grid, BT, 0, stream>>>(Mh, Mv, Vp, Tp, Wp, Cp, Ep, X, out,
                                      Bn, writeImag);
}